// Round 6
// baseline (400.952 us; speedup 1.0000x reference)
//
#include <hip/hip_runtime.h>

// GAT layer: N=100000 nodes, E=1.6M edges, IN=128, H=4, F=16 (H*F=64)
// fp32 in/out. Pipeline: h=x@W (register-blocked LDS GEMM, h stored bf16) ->
// CSR-by-dst (hist + hierarchical scan + fill storing src ids only) ->
// one wave per dst node: inline exp(leakyrelu(att)) weights (no max-shift:
// |e|<=~25 so exp is safely in fp32 range; softmax is shift-invariant),
// single-pass weighted aggregate of bf16 h rows, fused ELU.

#define NEG_SLOPE 0.2f

static __device__ __forceinline__ float b2f(unsigned short u) {
    union { unsigned u32; float f; } v; v.u32 = ((unsigned)u) << 16; return v.f;
}
static __device__ __forceinline__ unsigned f2b(float f) {
    union { float f; unsigned u; } v; v.f = f;
    return (v.u + 0x7fffu + ((v.u >> 16) & 1u)) >> 16;   // RNE
}

// ---------------- K1: h = x@W (fp32 VALU) + att_src/att_dst ---------------
// Block = 256 threads = 256 nodes; thread = 4 nodes x 16 cols (one head).
__global__ __launch_bounds__(256) void gemm_att_kernel(
    const float* __restrict__ x,       // [N,128]
    const float* __restrict__ W,       // [128,64]
    const float* __restrict__ a_src,   // [4,16]
    const float* __restrict__ a_dst,   // [4,16]
    unsigned short* __restrict__ h_out,// bf16 [N,64]
    float* __restrict__ att_s_o,       // [N,4]
    float* __restrict__ att_d_o,       // [N,4]
    int N)
{
    __shared__ float Wl[128 * 64];     // 32 KB
    int t = threadIdx.x;
    for (int i = t; i < 2048; i += 256)
        ((float4*)Wl)[i] = ((const float4*)W)[i];
    __syncthreads();

    int head = t & 3;
    int g = t >> 2;
    int n0 = blockIdx.x * 256 + g * 4;

    const float4* xr[4];
    #pragma unroll
    for (int j = 0; j < 4; ++j) {
        int nj = min(n0 + j, N - 1);
        xr[j] = (const float4*)(x + (size_t)nj * 128);
    }

    float acc[4][16];
    #pragma unroll
    for (int j = 0; j < 4; ++j)
        #pragma unroll
        for (int f = 0; f < 16; ++f) acc[j][f] = 0.f;

    const float4* Wl4 = (const float4*)Wl;
    for (int kk = 0; kk < 32; ++kk) {
        float xa[4][4];
        #pragma unroll
        for (int j = 0; j < 4; ++j)
            *(float4*)xa[j] = xr[j][kk];
        #pragma unroll
        for (int k4 = 0; k4 < 4; ++k4) {
            #pragma unroll
            for (int c = 0; c < 4; ++c) {
                float4 wv = Wl4[(kk * 4 + k4) * 16 + head * 4 + c];
                #pragma unroll
                for (int j = 0; j < 4; ++j) {
                    float xk = xa[j][k4];
                    acc[j][c * 4 + 0] = fmaf(xk, wv.x, acc[j][c * 4 + 0]);
                    acc[j][c * 4 + 1] = fmaf(xk, wv.y, acc[j][c * 4 + 1]);
                    acc[j][c * 4 + 2] = fmaf(xk, wv.z, acc[j][c * 4 + 2]);
                    acc[j][c * 4 + 3] = fmaf(xk, wv.w, acc[j][c * 4 + 3]);
                }
            }
        }
    }

    unsigned* h_out_u = (unsigned*)h_out;   // 2 bf16 per uint
    #pragma unroll
    for (int j = 0; j < 4; ++j) {
        int node = n0 + j;
        if (node >= N) break;
        float s = 0.f, d = 0.f;
        #pragma unroll
        for (int f = 0; f < 16; ++f) {
            s = fmaf(acc[j][f], a_src[head * 16 + f], s);
            d = fmaf(acc[j][f], a_dst[head * 16 + f], d);
        }
        att_s_o[(size_t)node * 4 + head] = s;
        att_d_o[(size_t)node * 4 + head] = d;

        uint4 pk[2];
        unsigned* pw = (unsigned*)pk;
        #pragma unroll
        for (int p = 0; p < 8; ++p)
            pw[p] = f2b(acc[j][2 * p]) | (f2b(acc[j][2 * p + 1]) << 16);
        uint4* ho = (uint4*)(h_out_u + (size_t)node * 32 + head * 8);
        ho[0] = pk[0];
        ho[1] = pk[1];
    }
}

// ---------------- K2: degree histogram ------------------------------------
__global__ __launch_bounds__(256) void hist_kernel(
    const int* __restrict__ dst, int* __restrict__ deg, int E)
{
    int e = blockIdx.x * blockDim.x + threadIdx.x;
    if (e < E) atomicAdd(&deg[dst[e]], 1);
}

// ---------------- K3a: per-block scan (1024 elems/block) ------------------
__global__ __launch_bounds__(1024) void scan1_kernel(
    const int* __restrict__ deg, int* __restrict__ rowstart,
    int* __restrict__ bsum, int N)
{
    __shared__ int sm[1024];
    int t = threadIdx.x;
    int i = blockIdx.x * 1024 + t;
    int v = (i < N) ? deg[i] : 0;
    sm[t] = v;
    __syncthreads();
    #pragma unroll
    for (int off = 1; off < 1024; off <<= 1) {
        int u = (t >= off) ? sm[t - off] : 0;
        __syncthreads();
        sm[t] += u;
        __syncthreads();
    }
    if (i < N) rowstart[i] = sm[t] - v;
    if (t == 1023) bsum[blockIdx.x] = sm[1023];
}

// ---------------- K3b: scan of block sums ---------------------------------
__global__ __launch_bounds__(1024) void scan2_kernel(
    int* __restrict__ bsum, int nb)
{
    __shared__ int sm[1024];
    int t = threadIdx.x;
    int v = (t < nb) ? bsum[t] : 0;
    sm[t] = v;
    __syncthreads();
    #pragma unroll
    for (int off = 1; off < 1024; off <<= 1) {
        int u = (t >= off) ? sm[t - off] : 0;
        __syncthreads();
        sm[t] += u;
        __syncthreads();
    }
    if (t < nb) bsum[t] = sm[t] - v;
}

// ---------------- K3c: add block offsets; materialize cursor --------------
__global__ __launch_bounds__(1024) void scan3_kernel(
    int* __restrict__ rowstart, int* __restrict__ cursor,
    const int* __restrict__ bsum, int N, int E)
{
    int i = blockIdx.x * 1024 + threadIdx.x;
    if (i < N) {
        int r = rowstart[i] + bsum[blockIdx.x];
        rowstart[i] = r;
        cursor[i] = r;
    }
    if (i == 0) rowstart[N] = E;
}

// ---------------- K4: fill CSR buckets with src ids -----------------------
__global__ __launch_bounds__(256) void fill_kernel(
    const int* __restrict__ src, const int* __restrict__ dst,
    int* __restrict__ cursor, int* __restrict__ elsrc, int E)
{
    int e = blockIdx.x * blockDim.x + threadIdx.x;
    if (e >= E) return;
    int d = dst[e];
    int p = atomicAdd(&cursor[d], 1);
    elsrc[p] = src[e];
}

// ---------------- K5: per-node weights + aggregate + ELU (one pass) -------
// One wave (64 lanes) per dst node; lane = head*16 + f.
__global__ __launch_bounds__(256) void agg_kernel(
    const int* __restrict__ elsrc,           // [E]
    const int* __restrict__ rowstart,        // [N+1]
    const float* __restrict__ att_s,         // [N,4]
    const float* __restrict__ att_d,         // [N,4]
    const unsigned short* __restrict__ hmat, // bf16 [N,64]
    float* __restrict__ out,                 // [N,64]
    int N)
{
    int node = blockIdx.x * 4 + (threadIdx.x >> 6);
    if (node >= N) return;
    int lane = threadIdx.x & 63;
    int h = lane >> 4;

    int beg = rowstart[node];
    int end = rowstart[node + 1];
    float ad = att_d[(size_t)node * 4 + h];

    float l = 0.f, acc = 0.f;
    int i = beg;
    for (; i + 3 < end; i += 4) {
        int s0 = elsrc[i], s1 = elsrc[i+1], s2 = elsrc[i+2], s3 = elsrc[i+3];
        float a0 = att_s[(size_t)s0 * 4 + h] + ad;
        float a1 = att_s[(size_t)s1 * 4 + h] + ad;
        float a2 = att_s[(size_t)s2 * 4 + h] + ad;
        float a3 = att_s[(size_t)s3 * 4 + h] + ad;
        float h0 = b2f(hmat[(size_t)s0 * 64 + lane]);
        float h1 = b2f(hmat[(size_t)s1 * 64 + lane]);
        float h2 = b2f(hmat[(size_t)s2 * 64 + lane]);
        float h3 = b2f(hmat[(size_t)s3 * 64 + lane]);
        a0 = fmaxf(a0, NEG_SLOPE * a0);
        a1 = fmaxf(a1, NEG_SLOPE * a1);
        a2 = fmaxf(a2, NEG_SLOPE * a2);
        a3 = fmaxf(a3, NEG_SLOPE * a3);
        float w0 = __expf(a0), w1 = __expf(a1), w2 = __expf(a2), w3 = __expf(a3);
        l += (w0 + w1) + (w2 + w3);
        acc = fmaf(w0, h0, acc);
        acc = fmaf(w1, h1, acc);
        acc = fmaf(w2, h2, acc);
        acc = fmaf(w3, h3, acc);
    }
    for (; i < end; ++i) {
        int s0 = elsrc[i];
        float a0 = att_s[(size_t)s0 * 4 + h] + ad;
        a0 = fmaxf(a0, NEG_SLOPE * a0);
        float w0 = __expf(a0);
        acc = fmaf(w0, b2f(hmat[(size_t)s0 * 64 + lane]), acc);
        l += w0;
    }

    float v = acc / (l + 1e-16f);
    v = (v > 0.f) ? v : (__expf(v) - 1.f);
    out[(size_t)node * 64 + lane] = v;
}

extern "C" void kernel_launch(void* const* d_in, const int* in_sizes, int n_in,
                              void* d_out, int out_size, void* d_ws, size_t ws_size,
                              hipStream_t stream) {
    const float* x     = (const float*)d_in[0];
    const int*   ei    = (const int*)d_in[1];
    const float* W     = (const float*)d_in[2];
    const float* a_src = (const float*)d_in[3];
    const float* a_dst = (const float*)d_in[4];

    int N = in_sizes[0] / 128;
    int E = in_sizes[1] / 2;
    const int* src = ei;
    const int* dst = ei + E;

    char* ws = (char*)d_ws;
    size_t off = 0;
    unsigned short* hmat = (unsigned short*)(ws + off); off += (size_t)N * 64 * 2; // 12.8 MB
    float* att_s = (float*)(ws + off);  off += (size_t)N * 4 * 4;
    float* att_d = (float*)(ws + off);  off += (size_t)N * 4 * 4;
    int* rowstart = (int*)(ws + off);   off += (size_t)(N + 1) * 4;
    int* cursor   = (int*)(ws + off);   off += (size_t)N * 4;
    int* elsrc    = (int*)(ws + off);   off += (size_t)E * 4;        // 6.4 MB
    int* bsum     = (int*)(ws + off);   off += 1024 * 4;
    int* deg      = (int*)(ws + off);   off += (size_t)N * 4;        // zeroed

    hipMemsetAsync(deg, 0, (size_t)N * 4, stream);

    int blocks1 = (N + 255) / 256;
    gemm_att_kernel<<<blocks1, 256, 0, stream>>>(x, W, a_src, a_dst,
                                                 hmat, att_s, att_d, N);

    int blocksE = (E + 255) / 256;
    hist_kernel<<<blocksE, 256, 0, stream>>>(dst, deg, E);

    int nb = (N + 1023) / 1024;               // 98 blocks
    scan1_kernel<<<nb, 1024, 0, stream>>>(deg, rowstart, bsum, N);
    scan2_kernel<<<1, 1024, 0, stream>>>(bsum, nb);
    scan3_kernel<<<nb, 1024, 0, stream>>>(rowstart, cursor, bsum, N, E);

    fill_kernel<<<blocksE, 256, 0, stream>>>(src, dst, cursor, elsrc, E);

    int blocksA = (N + 3) / 4;
    agg_kernel<<<blocksA, 256, 0, stream>>>(elsrc, rowstart, att_s, att_d,
                                            hmat, (float*)d_out, N);
}

// Round 7
// 270.298 us; speedup vs baseline: 1.4834x; 1.4834x over previous
//
#include <hip/hip_runtime.h>

// GAT layer: N=100000 nodes, E=1.6M edges, IN=128, H=4, F=16 (H*F=64)
// fp32 in/out. Pipeline:
//   gemm_att: h=x@W (register-blocked LDS GEMM, h stored bf16) + att_s/att_d
//   bcount/bscan:  coarse histogram of dst buckets (512 nodes/bucket)
//   bscatter:      LDS-staged radix partition of (src,dst) pairs -> coalesced
//                  bucket regions (fixes the 105 MB partial-line writeback of
//                  the naive per-edge scatter)
//   csr_fill:      one block per bucket: LDS hist+scan+scatter -> exact CSR
//                  (elsrc + rowstart), writes confined to one CU's L2 region
//   agg:           one wave per dst node, inline exp(leakyrelu) weights
//                  (no max-shift: |e|<~25, fp32-safe; softmax shift-invariant),
//                  single-pass bf16-h weighted aggregate, fused ELU.

#define NEG_SLOPE 0.2f
#define BSHIFT 9            // 512 nodes per bucket
#define BNODES 512
#define CH 4096             // edges per bscatter block (32 KB LDS staging)

static __device__ __forceinline__ float b2f(unsigned short u) {
    union { unsigned u32; float f; } v; v.u32 = ((unsigned)u) << 16; return v.f;
}
static __device__ __forceinline__ unsigned f2b(float f) {
    union { float f; unsigned u; } v; v.f = f;
    return (v.u + 0x7fffu + ((v.u >> 16) & 1u)) >> 16;   // RNE
}

// ---------------- K1: h = x@W (fp32 VALU) + att_src/att_dst ---------------
__global__ __launch_bounds__(256) void gemm_att_kernel(
    const float* __restrict__ x,       // [N,128]
    const float* __restrict__ W,       // [128,64]
    const float* __restrict__ a_src,   // [4,16]
    const float* __restrict__ a_dst,   // [4,16]
    unsigned short* __restrict__ h_out,// bf16 [N,64]
    float* __restrict__ att_s_o,       // [N,4]
    float* __restrict__ att_d_o,       // [N,4]
    int N)
{
    __shared__ float Wl[128 * 64];     // 32 KB
    int t = threadIdx.x;
    for (int i = t; i < 2048; i += 256)
        ((float4*)Wl)[i] = ((const float4*)W)[i];
    __syncthreads();

    int head = t & 3;
    int g = t >> 2;
    int n0 = blockIdx.x * 256 + g * 4;

    const float4* xr[4];
    #pragma unroll
    for (int j = 0; j < 4; ++j) {
        int nj = min(n0 + j, N - 1);
        xr[j] = (const float4*)(x + (size_t)nj * 128);
    }

    float acc[4][16];
    #pragma unroll
    for (int j = 0; j < 4; ++j)
        #pragma unroll
        for (int f = 0; f < 16; ++f) acc[j][f] = 0.f;

    const float4* Wl4 = (const float4*)Wl;
    for (int kk = 0; kk < 32; ++kk) {
        float xa[4][4];
        #pragma unroll
        for (int j = 0; j < 4; ++j)
            *(float4*)xa[j] = xr[j][kk];
        #pragma unroll
        for (int k4 = 0; k4 < 4; ++k4) {
            #pragma unroll
            for (int c = 0; c < 4; ++c) {
                float4 wv = Wl4[(kk * 4 + k4) * 16 + head * 4 + c];
                #pragma unroll
                for (int j = 0; j < 4; ++j) {
                    float xk = xa[j][k4];
                    acc[j][c * 4 + 0] = fmaf(xk, wv.x, acc[j][c * 4 + 0]);
                    acc[j][c * 4 + 1] = fmaf(xk, wv.y, acc[j][c * 4 + 1]);
                    acc[j][c * 4 + 2] = fmaf(xk, wv.z, acc[j][c * 4 + 2]);
                    acc[j][c * 4 + 3] = fmaf(xk, wv.w, acc[j][c * 4 + 3]);
                }
            }
        }
    }

    unsigned* h_out_u = (unsigned*)h_out;   // 2 bf16 per uint
    #pragma unroll
    for (int j = 0; j < 4; ++j) {
        int node = n0 + j;
        if (node >= N) break;
        float s = 0.f, d = 0.f;
        #pragma unroll
        for (int f = 0; f < 16; ++f) {
            s = fmaf(acc[j][f], a_src[head * 16 + f], s);
            d = fmaf(acc[j][f], a_dst[head * 16 + f], d);
        }
        att_s_o[(size_t)node * 4 + head] = s;
        att_d_o[(size_t)node * 4 + head] = d;

        uint4 pk[2];
        unsigned* pw = (unsigned*)pk;
        #pragma unroll
        for (int p = 0; p < 8; ++p)
            pw[p] = f2b(acc[j][2 * p]) | (f2b(acc[j][2 * p + 1]) << 16);
        uint4* ho = (uint4*)(h_out_u + (size_t)node * 32 + head * 8);
        ho[0] = pk[0];
        ho[1] = pk[1];
    }
}

// ---------------- K2: coarse bucket count ---------------------------------
__global__ __launch_bounds__(256) void bcount_kernel(
    const int* __restrict__ dst, int* __restrict__ bucketCount, int E)
{
    __shared__ int c[256];
    int t = threadIdx.x;
    c[t] = 0;
    __syncthreads();
    for (int e = blockIdx.x * 256 + t; e < E; e += gridDim.x * 256)
        atomicAdd(&c[dst[e] >> BSHIFT], 1);
    __syncthreads();
    if (c[t]) atomicAdd(&bucketCount[t], c[t]);
}

// ---------------- K3: scan bucket counts; init cursors --------------------
__global__ __launch_bounds__(256) void bscan_kernel(
    const int* __restrict__ bucketCount, int* __restrict__ bucketBase,
    int* __restrict__ bucketCursor, int nb, int E)
{
    __shared__ int sm[256];
    int t = threadIdx.x;
    int v = (t < nb) ? bucketCount[t] : 0;
    sm[t] = v;
    __syncthreads();
    #pragma unroll
    for (int off = 1; off < 256; off <<= 1) {
        int u = (t >= off) ? sm[t - off] : 0;
        __syncthreads();
        sm[t] += u;
        __syncthreads();
    }
    int excl = sm[t] - v;
    if (t <= nb) bucketBase[t] = (t == nb) ? E : excl;
    bucketCursor[t] = (t < nb) ? excl : 0;
}

// ---------------- K4: LDS-staged radix partition of (src,dst) -------------
__global__ __launch_bounds__(256) void bscatter_kernel(
    const int* __restrict__ src, const int* __restrict__ dst,
    int* __restrict__ bucketCursor, int2* __restrict__ pairs, int E)
{
    __shared__ int cnt[256], lo[256], gpos[256], cur[256], sm[256];
    __shared__ int2 staged[CH];        // 32 KB
    int t = threadIdx.x;
    int base = blockIdx.x * CH;
    int nloc = min(CH, E - base);

    cnt[t] = 0;
    __syncthreads();
    for (int i = t; i < nloc; i += 256)
        atomicAdd(&cnt[dst[base + i] >> BSHIFT], 1);
    __syncthreads();

    int v = cnt[t];
    sm[t] = v;
    __syncthreads();
    #pragma unroll
    for (int off = 1; off < 256; off <<= 1) {
        int u = (t >= off) ? sm[t - off] : 0;
        __syncthreads();
        sm[t] += u;
        __syncthreads();
    }
    lo[t] = sm[t] - v;
    cur[t] = lo[t];
    gpos[t] = (v > 0) ? atomicAdd(&bucketCursor[t], v) : 0;
    __syncthreads();

    for (int i = t; i < nloc; i += 256) {
        int d = dst[base + i];
        int s = src[base + i];
        int b = d >> BSHIFT;
        int k = atomicAdd(&cur[b], 1);
        staged[k] = make_int2(s, d);
    }
    __syncthreads();

    for (int i = t; i < nloc; i += 256) {
        int2 p = staged[i];
        int b = p.y >> BSHIFT;
        pairs[(size_t)gpos[b] + (i - lo[b])] = p;
    }
}

// ---------------- K5: per-bucket CSR fill (one block per bucket) ----------
__global__ __launch_bounds__(512) void csrfill_kernel(
    const int2* __restrict__ pairs, const int* __restrict__ bucketBase,
    int* __restrict__ rowstart, int* __restrict__ elsrc, int N, int E)
{
    __shared__ int hist[512], cur[512], sm[512];
    int b = blockIdx.x, t = threadIdx.x;
    int node_lo = b << BSHIFT;
    int nn = min(BNODES, N - node_lo);
    int ebase = bucketBase[b];
    int ecnt = bucketBase[b + 1] - ebase;

    hist[t] = 0;
    __syncthreads();
    for (int i = t; i < ecnt; i += 512)
        atomicAdd(&hist[pairs[ebase + i].y - node_lo], 1);
    __syncthreads();

    int v = hist[t];
    sm[t] = v;
    __syncthreads();
    #pragma unroll
    for (int off = 1; off < 512; off <<= 1) {
        int u = (t >= off) ? sm[t - off] : 0;
        __syncthreads();
        sm[t] += u;
        __syncthreads();
    }
    int excl = sm[t] - v;
    cur[t] = excl;
    if (t < nn) rowstart[node_lo + t] = ebase + excl;
    if (b == gridDim.x - 1 && t == 0) rowstart[N] = E;
    __syncthreads();

    for (int i = t; i < ecnt; i += 512) {
        int2 p = pairs[ebase + i];
        int k = atomicAdd(&cur[p.y - node_lo], 1);
        elsrc[ebase + k] = p.x;
    }
}

// ---------------- K6: per-node weights + aggregate + ELU (one pass) -------
__global__ __launch_bounds__(256) void agg_kernel(
    const int* __restrict__ elsrc,           // [E]
    const int* __restrict__ rowstart,        // [N+1]
    const float* __restrict__ att_s,         // [N,4]
    const float* __restrict__ att_d,         // [N,4]
    const unsigned short* __restrict__ hmat, // bf16 [N,64]
    float* __restrict__ out,                 // [N,64]
    int N)
{
    int node = blockIdx.x * 4 + (threadIdx.x >> 6);
    if (node >= N) return;
    int lane = threadIdx.x & 63;
    int h = lane >> 4;

    int beg = rowstart[node];
    int end = rowstart[node + 1];
    float ad = att_d[(size_t)node * 4 + h];

    float l = 0.f, acc = 0.f;
    int i = beg;
    for (; i + 3 < end; i += 4) {
        int s0 = elsrc[i], s1 = elsrc[i+1], s2 = elsrc[i+2], s3 = elsrc[i+3];
        float a0 = att_s[(size_t)s0 * 4 + h] + ad;
        float a1 = att_s[(size_t)s1 * 4 + h] + ad;
        float a2 = att_s[(size_t)s2 * 4 + h] + ad;
        float a3 = att_s[(size_t)s3 * 4 + h] + ad;
        float h0 = b2f(hmat[(size_t)s0 * 64 + lane]);
        float h1 = b2f(hmat[(size_t)s1 * 64 + lane]);
        float h2 = b2f(hmat[(size_t)s2 * 64 + lane]);
        float h3 = b2f(hmat[(size_t)s3 * 64 + lane]);
        a0 = fmaxf(a0, NEG_SLOPE * a0);
        a1 = fmaxf(a1, NEG_SLOPE * a1);
        a2 = fmaxf(a2, NEG_SLOPE * a2);
        a3 = fmaxf(a3, NEG_SLOPE * a3);
        float w0 = __expf(a0), w1 = __expf(a1), w2 = __expf(a2), w3 = __expf(a3);
        l += (w0 + w1) + (w2 + w3);
        acc = fmaf(w0, h0, acc);
        acc = fmaf(w1, h1, acc);
        acc = fmaf(w2, h2, acc);
        acc = fmaf(w3, h3, acc);
    }
    for (; i < end; ++i) {
        int s0 = elsrc[i];
        float a0 = att_s[(size_t)s0 * 4 + h] + ad;
        a0 = fmaxf(a0, NEG_SLOPE * a0);
        float w0 = __expf(a0);
        acc = fmaf(w0, b2f(hmat[(size_t)s0 * 64 + lane]), acc);
        l += w0;
    }

    float v = acc / (l + 1e-16f);
    v = (v > 0.f) ? v : (__expf(v) - 1.f);
    out[(size_t)node * 64 + lane] = v;
}

extern "C" void kernel_launch(void* const* d_in, const int* in_sizes, int n_in,
                              void* d_out, int out_size, void* d_ws, size_t ws_size,
                              hipStream_t stream) {
    const float* x     = (const float*)d_in[0];
    const int*   ei    = (const int*)d_in[1];
    const float* W     = (const float*)d_in[2];
    const float* a_src = (const float*)d_in[3];
    const float* a_dst = (const float*)d_in[4];

    int N = in_sizes[0] / 128;
    int E = in_sizes[1] / 2;
    const int* src = ei;
    const int* dst = ei + E;
    int nb = (N + BNODES - 1) / BNODES;       // 196 buckets

    char* ws = (char*)d_ws;
    size_t off = 0;
    unsigned short* hmat = (unsigned short*)(ws + off); off += (size_t)N * 64 * 2; // 12.8 MB
    float* att_s = (float*)(ws + off);  off += (size_t)N * 4 * 4;
    float* att_d = (float*)(ws + off);  off += (size_t)N * 4 * 4;
    int* rowstart = (int*)(ws + off);   off += (size_t)(N + 1) * 4;
    int* elsrc    = (int*)(ws + off);   off += (size_t)E * 4;        // 6.4 MB
    int2* pairs   = (int2*)(ws + off);  off += (size_t)E * 8;        // 12.8 MB
    int* bucketBase   = (int*)(ws + off); off += 260 * 4;
    int* bucketCursor = (int*)(ws + off); off += 256 * 4;
    int* bucketCount  = (int*)(ws + off); off += 256 * 4;            // zeroed

    hipMemsetAsync(bucketCount, 0, 256 * 4, stream);

    int blocks1 = (N + 255) / 256;
    gemm_att_kernel<<<blocks1, 256, 0, stream>>>(x, W, a_src, a_dst,
                                                 hmat, att_s, att_d, N);

    bcount_kernel<<<512, 256, 0, stream>>>(dst, bucketCount, E);
    bscan_kernel<<<1, 256, 0, stream>>>(bucketCount, bucketBase, bucketCursor, nb, E);

    int blocksS = (E + CH - 1) / CH;          // 391
    bscatter_kernel<<<blocksS, 256, 0, stream>>>(src, dst, bucketCursor, pairs, E);

    csrfill_kernel<<<nb, 512, 0, stream>>>(pairs, bucketBase, rowstart, elsrc, N, E);

    int blocksA = (N + 3) / 4;
    agg_kernel<<<blocksA, 256, 0, stream>>>(elsrc, rowstart, att_s, att_d,
                                            hmat, (float*)d_out, N);
}